// Round 5
// baseline (332.767 us; speedup 1.0000x reference)
//
#include <hip/hip_runtime.h>

#define B_ 4
#define W_ 2048
#define C_ 1024
#define NH 16
#define KH 64

typedef __attribute__((ext_vector_type(8))) short short8;
typedef __attribute__((ext_vector_type(4))) short s16x4;
typedef __attribute__((ext_vector_type(4))) float f32x4;

__device__ __forceinline__ short f2bf(float f) {
    unsigned u = __builtin_bit_cast(unsigned, f);
    u = (u + 0x7FFFu + ((u >> 16) & 1u)) >> 16;
    return (short)u;
}

// ---------------- metric[n] = P[n] @ P[n]^T ----------------
__global__ __launch_bounds__(256) void k_metric(const float* __restrict__ P, float* __restrict__ M) {
    int n = blockIdx.x;
    __shared__ float sP[KH * KH];
    __shared__ float sPt[KH * 65];
    const float* Pn = P + n * KH * KH;
    for (int i = threadIdx.x; i < KH * KH; i += 256) {
        float v = Pn[i];
        sP[i] = v;
        sPt[(i & 63) * 65 + (i >> 6)] = v;
    }
    __syncthreads();
    float* Mn = M + n * KH * KH;
    for (int e = threadIdx.x; e < KH * KH; e += 256) {
        int i = e >> 6, k = e & 63;
        float s = 0.f;
        #pragma unroll 8
        for (int j = 0; j < KH; ++j) s += sP[i * KH + j] * sPt[j * 65 + k];
        Mn[e] = s;
    }
}

// ---------------- Wq[n*64+jj][c] = 0.125 * sum_k M[n][k][jj] * Wp[n*64+k][c] ----------------
__global__ __launch_bounds__(256) void k_wq(const float* __restrict__ M, const float* __restrict__ Wp,
                                            short* __restrict__ Wq) {
    int n = blockIdx.y, cseg = blockIdx.x;
    __shared__ float sM[KH * KH];
    __shared__ float sW[KH * KH];
    for (int i = threadIdx.x; i < KH * KH; i += 256) {
        sM[i] = M[n * KH * KH + i];
        int r = i >> 6, c = i & 63;
        sW[i] = Wp[(n * KH + r) * C_ + cseg * KH + c];
    }
    __syncthreads();
    for (int e = threadIdx.x; e < KH * KH; e += 256) {
        int jj = e >> 6, c = e & 63;
        float s = 0.f;
        #pragma unroll 8
        for (int k = 0; k < KH; ++k) s += sM[k * KH + jj] * sW[k * KH + c];
        Wq[(n * KH + jj) * C_ + cseg * KH + c] = f2bf(s * 0.125f);   // fold 1/sqrt(K)
    }
}

// ---------------- Wf[o][n*64+k] = sum_j T[n][k][j] * Wm[o][n*64+j] ----------------
__global__ __launch_bounds__(256) void k_wf(const float* __restrict__ T, const float* __restrict__ Wm,
                                            short* __restrict__ Wf) {
    int n = blockIdx.y, oseg = blockIdx.x;
    __shared__ float sTt[KH * 65];
    __shared__ float sW[KH * KH];
    for (int i = threadIdx.x; i < KH * KH; i += 256) {
        sTt[(i & 63) * 65 + (i >> 6)] = T[n * KH * KH + i];
        int r = i >> 6, c = i & 63;
        sW[i] = Wm[(oseg * KH + r) * C_ + n * KH + c];
    }
    __syncthreads();
    for (int e = threadIdx.x; e < KH * KH; e += 256) {
        int r = e >> 6, k = e & 63;
        float s = 0.f;
        #pragma unroll 8
        for (int j = 0; j < KH; ++j) s += sTt[j * 65 + k] * sW[r * KH + j];
        Wf[(oseg * KH + r) * C_ + n * KH + k] = f2bf(s);
    }
}

// ---------------- fp32 -> bf16 convert ----------------
__global__ __launch_bounds__(256) void k_cvt(const float* __restrict__ src, short* __restrict__ dst, int n4) {
    int i = blockIdx.x * 256 + threadIdx.x;
    if (i < n4) {
        float4 v = ((const float4*)src)[i];
        short4 o;
        o.x = f2bf(v.x); o.y = f2bf(v.y); o.z = f2bf(v.z); o.w = f2bf(v.w);
        ((short4*)dst)[i] = o;
    }
}

// ---------------- per-(b,n) transpose: Ptg[(b*16+n)*64+k][w] = Pj[b][w][n*64+k] ----------------
__global__ __launch_bounds__(256) void k_tr(const short* __restrict__ src, short* __restrict__ dst) {
    int wt = blockIdx.x, bn = blockIdx.y;
    int b = bn >> 4, n = bn & 15;
    __shared__ short ld[64 * 72];
    int t = threadIdx.x;
    #pragma unroll
    for (int e = 0; e < 2; ++e) {
        int ch = e * 256 + t, row = ch >> 3, sub = ch & 7;
        *(short8*)&ld[row * 72 + sub * 8] =
            *(const short8*)&src[(b * W_ + wt * 64 + row) * C_ + n * KH + sub * 8];
    }
    __syncthreads();
    #pragma unroll
    for (int e = 0; e < 2; ++e) {
        int ch = e * 256 + t, krow = ch >> 3, sub = ch & 7;
        short8 v;
        #pragma unroll
        for (int j = 0; j < 8; ++j) v[j] = ld[(sub * 8 + j) * 72 + krow];
        *(short8*)&dst[(bn * KH + krow) * W_ + wt * 64 + sub * 8] = v;
    }
}

// ---------------- Out[M][1024] = A[M][1024] @ Bw[1024][1024]^T ----------------
// m97-style: global_load_lds width=16 into unpadded LDS, k-chunk XOR swizzle on global side.
template <bool OUT_FP32>
__global__ __launch_bounds__(256) void k_gemm(const short* __restrict__ A, const short* __restrict__ Bw,
                                              void* __restrict__ Out) {
    __shared__ short As[128 * 64];
    __shared__ short Bs[128 * 64];
    int bm = blockIdx.y, bn = blockIdx.x;
    int t = threadIdx.x;
    int wave = t >> 6, lane = t & 63;
    int q = lane >> 4, c = lane & 15;
    int wy = wave >> 1, wx = wave & 1;
    f32x4 acc[4][4] = {};
    int xsw = (c & 7);                       // reader-side swizzle
    for (int k0 = 0; k0 < C_; k0 += 64) {
        __syncthreads();
        #pragma unroll
        for (int e = 0; e < 4; ++e) {
            int row = (e * 256 + t) >> 3;
            int ks = ((t & 7) ^ (row & 7)) * 8;          // swizzled k-chunk (global side)
            __builtin_amdgcn_global_load_lds(
                (const __attribute__((address_space(1))) void*)&A[(bm * 128 + row) * C_ + k0 + ks],
                (__attribute__((address_space(3))) void*)&As[e * 2048 + wave * 512], 16, 0, 0);
            __builtin_amdgcn_global_load_lds(
                (const __attribute__((address_space(1))) void*)&Bw[(bn * 128 + row) * C_ + k0 + ks],
                (__attribute__((address_space(3))) void*)&Bs[e * 2048 + wave * 512], 16, 0, 0);
        }
        __syncthreads();
        #pragma unroll
        for (int kk = 0; kk < 64; kk += 32) {
            int o = kk >> 3;                             // 0 or 4
            int xo = ((o + q) ^ xsw) * 8;
            short8 af[4], bfr[4];
            #pragma unroll
            for (int i = 0; i < 4; ++i)
                af[i] = *(const short8*)&As[(wy * 64 + i * 16 + c) * 64 + xo];
            #pragma unroll
            for (int j = 0; j < 4; ++j)
                bfr[j] = *(const short8*)&Bs[(wx * 64 + j * 16 + c) * 64 + xo];
            #pragma unroll
            for (int i = 0; i < 4; ++i)
                #pragma unroll
                for (int j = 0; j < 4; ++j)
                    acc[i][j] = __builtin_amdgcn_mfma_f32_16x16x32_bf16(af[i], bfr[j], acc[i][j], 0, 0, 0);
        }
    }
    #pragma unroll
    for (int i = 0; i < 4; ++i)
        #pragma unroll
        for (int j = 0; j < 4; ++j)
            #pragma unroll
            for (int r = 0; r < 4; ++r) {
                int row = bm * 128 + wy * 64 + i * 16 + q * 4 + r;
                int col = bn * 128 + wx * 64 + j * 16 + c;
                if (OUT_FP32) ((float*)Out)[row * C_ + col] = acc[i][j][r];
                else ((short*)Out)[row * C_ + col] = f2bf(acc[i][j][r]);
            }
}

// ---------------- fused causal scores->nudged: per-wave St, dbuf + prefetch, 2 barriers/iter ----------------
// grid (16 wt, 16 n, 4 b) x 512 (8 waves). Each wave owns 16 w-rows for BOTH QK and PV.
// Barrier 1: staging visible (+ dbuf reuse safety). Barrier 2: St write -> PV read (explicit
// cross-phase sync; round-4's barrier-free in-wave exchange is the prime suspect for the
// post-timing divergence and is removed).
__global__ __launch_bounds__(512, 4) void k_flash(const short* __restrict__ Qm, const short* __restrict__ Pj,
                                                  const short* __restrict__ Ptg, short* __restrict__ Nd) {
    int wt = 15 - (int)blockIdx.x;     // heavy tiles first
    int n = blockIdx.y, b = blockIdx.z;
    int t = threadIdx.x, wave = t >> 6, lane = t & 63;
    int q = lane >> 4, c = lane & 15;
    __shared__ short Ps[2][64 * 72];   // P tile   [v][k], double-buffered
    __shared__ short Pt[2][64 * 72];   // P^T tile [k][v], double-buffered
    __shared__ short St[8][16 * 72];   // per-wave S strip [w][v]
    int w0 = wt * 128;
    int wrow = w0 + wave * 16 + c;     // this wave's w row (B-frag row & mask col)

    short8 bq0 = *(const short8*)&Qm[(b * W_ + wrow) * C_ + n * KH + q * 8];
    short8 bq1 = *(const short8*)&Qm[(b * W_ + wrow) * C_ + n * KH + 32 + q * 8];

    int srow = t >> 3, ssub = t & 7;   // 512 threads cover 64 rows x 8 chunks
    const short* psrc = &Pj[(b * W_ + srow) * C_ + n * KH + ssub * 8];
    const short* tsrc = &Ptg[((b * NH + n) * KH + srow) * W_ + ssub * 8];
    int sdst = srow * 72 + ssub * 8;

    f32x4 oc[4] = {};
    int vmax = 2 * wt + 1;
    short8 pfA = *(const short8*)psrc;          // prefetch v-tile 0
    short8 pfB = *(const short8*)tsrc;

    for (int vt = 0; vt <= vmax; ++vt) {
        int bb = vt & 1;
        *(short8*)&Ps[bb][sdst] = pfA;          // vmcnt wait lands here, 1 iter after issue
        *(short8*)&Pt[bb][sdst] = pfB;
        if (vt < vmax) {
            pfA = *(const short8*)(psrc + (size_t)(vt + 1) * 64 * C_);
            pfB = *(const short8*)(tsrc + (vt + 1) * 64);
        }
        __syncthreads();                        // staging visible; buf bb safe to read
        bool diag = (vt >= 2 * wt);
        #pragma unroll
        for (int ct = 0; ct < 4; ++ct) {
            short8 a0 = *(const short8*)&Ps[bb][(ct * 16 + c) * 72 + q * 8];
            short8 a1 = *(const short8*)&Ps[bb][(ct * 16 + c) * 72 + 32 + q * 8];
            f32x4 st = {};
            st = __builtin_amdgcn_mfma_f32_16x16x32_bf16(a0, bq0, st, 0, 0, 0);
            st = __builtin_amdgcn_mfma_f32_16x16x32_bf16(a1, bq1, st, 0, 0, 0);
            int vbase = vt * 64 + ct * 16 + q * 4;
            s16x4 pk;
            #pragma unroll
            for (int r = 0; r < 4; ++r) {
                float v = st[r];
                if (diag && (vbase + r > wrow)) v = 0.f;
                pk[r] = f2bf(v);
            }
            *(s16x4*)&St[wave][c * 72 + ct * 16 + q * 4] = pk;
        }
        __syncthreads();                        // St visible before PV reads
        short8 as0 = *(const short8*)&St[wave][c * 72 + q * 8];
        short8 as1 = *(const short8*)&St[wave][c * 72 + 32 + q * 8];
        #pragma unroll
        for (int ct2 = 0; ct2 < 4; ++ct2) {
            short8 bp0 = *(const short8*)&Pt[bb][(ct2 * 16 + c) * 72 + q * 8];
            short8 bp1 = *(const short8*)&Pt[bb][(ct2 * 16 + c) * 72 + 32 + q * 8];
            oc[ct2] = __builtin_amdgcn_mfma_f32_16x16x32_bf16(as0, bp0, oc[ct2], 0, 0, 0);
            oc[ct2] = __builtin_amdgcn_mfma_f32_16x16x32_bf16(as1, bp1, oc[ct2], 0, 0, 0);
        }
    }
    #pragma unroll
    for (int ct2 = 0; ct2 < 4; ++ct2)
        #pragma unroll
        for (int r = 0; r < 4; ++r)
            Nd[(b * W_ + w0 + wave * 16 + q * 4 + r) * C_ + n * KH + ct2 * 16 + c] = f2bf(oc[ct2][r]);
}

extern "C" void kernel_launch(void* const* d_in, const int* in_sizes, int n_in,
                              void* d_out, int out_size, void* d_ws, size_t ws_size,
                              hipStream_t stream) {
    const float* x  = (const float*)d_in[0];
    const float* Wp = (const float*)d_in[1];
    const float* Pm = (const float*)d_in[2];
    const float* Tr = (const float*)d_in[3];
    const float* Wm = (const float*)d_in[4];
    float* out = (float*)d_out;
    char* ws = (char*)d_ws;

    const size_t MB = 1024 * 1024;
    float* metric = (float*)ws;                       // 256 KB
    short* wq16 = (short*)(ws + 256 * 1024);          // 2 MB
    short* wf16 = (short*)(ws + 256 * 1024 + 2 * MB); // 2 MB
    short* wp16 = (short*)(ws + 256 * 1024 + 4 * MB); // 2 MB
    short* x16  = (short*)(ws + 256 * 1024 + 6 * MB); // 16 MB
    short* pj16 = x16 + 8 * MB;                       // 16 MB
    short* qm16 = pj16 + 8 * MB;                      // 16 MB
    short* ptg  = qm16 + 8 * MB;                      // 16 MB
    short* nd16 = x16;                                // alias: x16 dead after GEMMs

    k_metric<<<dim3(NH), dim3(256), 0, stream>>>(Pm, metric);
    k_wq<<<dim3(16, NH), dim3(256), 0, stream>>>(metric, Wp, wq16);
    k_wf<<<dim3(16, NH), dim3(256), 0, stream>>>(Tr, Wm, wf16);
    k_cvt<<<dim3(8192), dim3(256), 0, stream>>>(x, x16, (B_ * W_ * C_) / 4);
    k_cvt<<<dim3(1024), dim3(256), 0, stream>>>(Wp, wp16, (C_ * C_) / 4);

    k_gemm<false><<<dim3(8, 64), dim3(256), 0, stream>>>(x16, wp16, (void*)pj16);
    k_gemm<false><<<dim3(8, 64), dim3(256), 0, stream>>>(x16, wq16, (void*)qm16);
    k_tr<<<dim3(32, 64), dim3(256), 0, stream>>>(pj16, ptg);
    k_flash<<<dim3(16, NH, B_), dim3(512), 0, stream>>>(qm16, pj16, ptg, nd16);
    k_gemm<true><<<dim3(8, 64), dim3(256), 0, stream>>>(nd16, wf16, (void*)out);
}

// Round 7
// 283.577 us; speedup vs baseline: 1.1735x; 1.1735x over previous
//
#include <hip/hip_runtime.h>

#define B_ 4
#define W_ 2048
#define C_ 1024
#define NH 16
#define KH 64

typedef __attribute__((ext_vector_type(8))) short short8;
typedef __attribute__((ext_vector_type(4))) short s16x4;
typedef __attribute__((ext_vector_type(4))) float f32x4;

__device__ __forceinline__ short f2bf(float f) {
    unsigned u = __builtin_bit_cast(unsigned, f);
    u = (u + 0x7FFFu + ((u >> 16) & 1u)) >> 16;
    return (short)u;
}
__device__ __forceinline__ float bf2f(short h) {
    return __builtin_bit_cast(float, ((unsigned)(unsigned short)h) << 16);
}

// ---------------- metric[n] = P[n] @ P[n]^T ----------------
__global__ __launch_bounds__(256) void k_metric(const float* __restrict__ P, float* __restrict__ M) {
    int n = blockIdx.x;
    __shared__ float sP[KH * KH];
    __shared__ float sPt[KH * 65];
    const float* Pn = P + n * KH * KH;
    for (int i = threadIdx.x; i < KH * KH; i += 256) {
        float v = Pn[i];
        sP[i] = v;
        sPt[(i & 63) * 65 + (i >> 6)] = v;
    }
    __syncthreads();
    float* Mn = M + n * KH * KH;
    for (int e = threadIdx.x; e < KH * KH; e += 256) {
        int i = e >> 6, k = e & 63;
        float s = 0.f;
        #pragma unroll 8
        for (int j = 0; j < KH; ++j) s += sP[i * KH + j] * sPt[j * 65 + k];
        Mn[e] = s;
    }
}

// ---------------- Wq[n*64+jj][c] = 0.125 * sum_k M[n][k][jj] * Wp[n*64+k][c] ----------------
__global__ __launch_bounds__(256) void k_wq(const float* __restrict__ M, const float* __restrict__ Wp,
                                            short* __restrict__ Wq) {
    int n = blockIdx.y, cseg = blockIdx.x;
    __shared__ float sM[KH * KH];
    __shared__ float sW[KH * KH];
    for (int i = threadIdx.x; i < KH * KH; i += 256) {
        sM[i] = M[n * KH * KH + i];
        int r = i >> 6, c = i & 63;
        sW[i] = Wp[(n * KH + r) * C_ + cseg * KH + c];
    }
    __syncthreads();
    for (int e = threadIdx.x; e < KH * KH; e += 256) {
        int jj = e >> 6, c = e & 63;
        float s = 0.f;
        #pragma unroll 8
        for (int k = 0; k < KH; ++k) s += sM[k * KH + jj] * sW[k * KH + c];
        Wq[(n * KH + jj) * C_ + cseg * KH + c] = f2bf(s * 0.125f);   // fold 1/sqrt(K)
    }
}

// ---------------- Wf[o][n*64+k] = sum_j T[n][k][j] * Wm[o][n*64+j] ----------------
__global__ __launch_bounds__(256) void k_wf(const float* __restrict__ T, const float* __restrict__ Wm,
                                            short* __restrict__ Wf) {
    int n = blockIdx.y, oseg = blockIdx.x;
    __shared__ float sTt[KH * 65];
    __shared__ float sW[KH * KH];
    for (int i = threadIdx.x; i < KH * KH; i += 256) {
        sTt[(i & 63) * 65 + (i >> 6)] = T[n * KH * KH + i];
        int r = i >> 6, c = i & 63;
        sW[i] = Wm[(oseg * KH + r) * C_ + n * KH + c];
    }
    __syncthreads();
    for (int e = threadIdx.x; e < KH * KH; e += 256) {
        int r = e >> 6, k = e & 63;
        float s = 0.f;
        #pragma unroll 8
        for (int j = 0; j < KH; ++j) s += sTt[j * 65 + k] * sW[r * KH + j];
        Wf[(oseg * KH + r) * C_ + n * KH + k] = f2bf(s);
    }
}

// ---------------- fp32 -> bf16 convert ----------------
__global__ __launch_bounds__(256) void k_cvt(const float* __restrict__ src, short* __restrict__ dst, int n4) {
    int i = blockIdx.x * 256 + threadIdx.x;
    if (i < n4) {
        float4 v = ((const float4*)src)[i];
        short4 o;
        o.x = f2bf(v.x); o.y = f2bf(v.y); o.z = f2bf(v.z); o.w = f2bf(v.w);
        ((short4*)dst)[i] = o;
    }
}

// ---------------- Out[M][OC] = A[M][1024] @ Bw[OC][1024]^T ----------------
// m97-style: global_load_lds width=16 into unpadded LDS, k-chunk XOR swizzle on global side.
template <int OC, bool OUT_FP32>
__global__ __launch_bounds__(256) void k_gemm(const short* __restrict__ A, const short* __restrict__ Bw,
                                              void* __restrict__ Out) {
    __shared__ short As[128 * 64];
    __shared__ short Bs[128 * 64];
    int bm = blockIdx.y, bn = blockIdx.x;
    int t = threadIdx.x;
    int wave = t >> 6, lane = t & 63;
    int q = lane >> 4, c = lane & 15;
    int wy = wave >> 1, wx = wave & 1;
    f32x4 acc[4][4] = {};
    int xsw = (c & 7);                       // reader-side swizzle
    for (int k0 = 0; k0 < C_; k0 += 64) {
        __syncthreads();
        #pragma unroll
        for (int e = 0; e < 4; ++e) {
            int row = (e * 256 + t) >> 3;
            int ks = ((t & 7) ^ (row & 7)) * 8;          // swizzled k-chunk (global side)
            __builtin_amdgcn_global_load_lds(
                (const __attribute__((address_space(1))) void*)&A[(size_t)(bm * 128 + row) * C_ + k0 + ks],
                (__attribute__((address_space(3))) void*)&As[e * 2048 + wave * 512], 16, 0, 0);
            __builtin_amdgcn_global_load_lds(
                (const __attribute__((address_space(1))) void*)&Bw[(size_t)(bn * 128 + row) * C_ + k0 + ks],
                (__attribute__((address_space(3))) void*)&Bs[e * 2048 + wave * 512], 16, 0, 0);
        }
        __syncthreads();
        #pragma unroll
        for (int kk = 0; kk < 64; kk += 32) {
            int o = kk >> 3;                             // 0 or 4
            int xo = ((o + q) ^ xsw) * 8;
            short8 af[4], bfr[4];
            #pragma unroll
            for (int i = 0; i < 4; ++i)
                af[i] = *(const short8*)&As[(wy * 64 + i * 16 + c) * 64 + xo];
            #pragma unroll
            for (int j = 0; j < 4; ++j)
                bfr[j] = *(const short8*)&Bs[(wx * 64 + j * 16 + c) * 64 + xo];
            #pragma unroll
            for (int i = 0; i < 4; ++i)
                #pragma unroll
                for (int j = 0; j < 4; ++j)
                    acc[i][j] = __builtin_amdgcn_mfma_f32_16x16x32_bf16(af[i], bfr[j], acc[i][j], 0, 0, 0);
        }
    }
    #pragma unroll
    for (int i = 0; i < 4; ++i)
        #pragma unroll
        for (int j = 0; j < 4; ++j)
            #pragma unroll
            for (int r = 0; r < 4; ++r) {
                int row = bm * 128 + wy * 64 + i * 16 + q * 4 + r;
                int col = bn * 128 + wx * 64 + j * 16 + c;
                if (OUT_FP32) ((float*)Out)[(size_t)row * OC + col] = acc[i][j][r];
                else ((short*)Out)[(size_t)row * OC + col] = f2bf(acc[i][j][r]);
            }
}

// ---------------- k_prefix: per (b,n), exclusive prefix of C_c = sum_{v<64c} P[v]^T P[v] ----------------
// 64 blocks x 256 thr (4 waves). C kept in fp32 MFMA acc regs; emitted per chunk as bf16 hi+lo
// in [j][k] layout (C symmetric -> also [k][j]). acc layout IS the store layout (s16x4 vec stores).
__global__ __launch_bounds__(256) void k_prefix(const short* __restrict__ pjqm,
                                                short* __restrict__ Chi, short* __restrict__ Clo) {
    int bn = blockIdx.x;          // b*16+n
    int b = bn >> 4, n = bn & 15;
    int t = threadIdx.x, wave = t >> 6, lane = t & 63;
    int q = lane >> 4, c = lane & 15;
    __shared__ short Pt_s[64 * 72];   // P_c^T  [k][v]
    f32x4 acc[4] = {};                // acc[tj][r] = C[k=wave*16+q*4+r][j=tj*16+c]
    for (int cc = 0; cc < 32; ++cc) {
        __syncthreads();              // Pt_s reuse guard
        #pragma unroll
        for (int e = 0; e < 2; ++e) {
            int chv = e * 256 + t, row = chv >> 3, sub = chv & 7;   // row = v
            short8 p8 = *(const short8*)&pjqm[(size_t)(b * W_ + cc * 64 + row) * 2048 + n * KH + sub * 8];
            #pragma unroll
            for (int j = 0; j < 8; ++j) Pt_s[(sub * 8 + j) * 72 + row] = p8[j];
        }
        __syncthreads();
        // exclusive prefix write (acc = C before this chunk)
        size_t cbase = ((size_t)bn * 32 + cc) * 4096;
        #pragma unroll
        for (int tj = 0; tj < 4; ++tj) {
            s16x4 hi, lo;
            #pragma unroll
            for (int r = 0; r < 4; ++r) {
                float a = acc[tj][r];
                short h = f2bf(a);
                hi[r] = h;
                lo[r] = f2bf(a - bf2f(h));
            }
            size_t off = cbase + (size_t)(tj * 16 + c) * 64 + wave * 16 + q * 4;  // [j][k], sym
            *(s16x4*)&Chi[off] = hi;
            *(s16x4*)&Clo[off] = lo;
        }
        if (cc < 31) {                // accumulate O_cc = P^T P
            short8 a0 = *(const short8*)&Pt_s[(wave * 16 + c) * 72 + q * 8];
            short8 a1 = *(const short8*)&Pt_s[(wave * 16 + c) * 72 + 32 + q * 8];
            #pragma unroll
            for (int tj = 0; tj < 4; ++tj) {
                short8 b0 = *(const short8*)&Pt_s[(tj * 16 + c) * 72 + q * 8];
                short8 b1 = *(const short8*)&Pt_s[(tj * 16 + c) * 72 + 32 + q * 8];
                acc[tj] = __builtin_amdgcn_mfma_f32_16x16x32_bf16(a0, b0, acc[tj], 0, 0, 0);
                acc[tj] = __builtin_amdgcn_mfma_f32_16x16x32_bf16(a1, b1, acc[tj], 0, 0, 0);
            }
        }
    }
}

// ---------------- k_chunk: nudged_c = causal_intra(QM_c,P_c) + QM_c @ (Chi+Clo) ----------------
// grid (32 chunk, 16 n, 4 b) x 256 thr (4 waves); one-shot, 32 MFMA/wave, 2 barriers.
__global__ __launch_bounds__(256) void k_chunk(const short* __restrict__ pjqm,
                                               const short* __restrict__ Chi, const short* __restrict__ Clo,
                                               short* __restrict__ Nd) {
    int cc = blockIdx.x, n = blockIdx.y, b = blockIdx.z;
    int t = threadIdx.x, wave = t >> 6, lane = t & 63;
    int q = lane >> 4, c = lane & 15;
    __shared__ short Ps[64 * 72];     // P_c   [v][k]
    __shared__ short Pt_s[64 * 72];   // P_c^T [k][v]
    __shared__ short Ch[64 * 72];     // C_hi  [j][k]
    __shared__ short Cl[64 * 72];     // C_lo  [j][k]
    __shared__ short St[4][16 * 72];  // per-wave S strip [w][v]
    int w0g = b * W_ + cc * 64;

    // QM rows for this wave (dual-use: B-frag in QK, A-frag in QM@C).
    // ROUND-6 BUG FIX: each lane must load its quad's k-chunk (+ q*8).
    const short* qmrow = &pjqm[(size_t)(w0g + wave * 16 + c) * 2048 + 1024 + n * KH];
    short8 bq0 = *(const short8*)(qmrow + q * 8);
    short8 bq1 = *(const short8*)(qmrow + 32 + q * 8);

    #pragma unroll
    for (int e = 0; e < 2; ++e) {
        int chv = e * 256 + t, row = chv >> 3, sub = chv & 7;
        short8 p8 = *(const short8*)&pjqm[(size_t)(w0g + row) * 2048 + n * KH + sub * 8];
        *(short8*)&Ps[row * 72 + sub * 8] = p8;
        #pragma unroll
        for (int j = 0; j < 8; ++j) Pt_s[(sub * 8 + j) * 72 + row] = p8[j];
        size_t cbase = ((size_t)((b * NH + n) * 32 + cc)) * 4096;
        *(short8*)&Ch[row * 72 + sub * 8] = *(const short8*)&Chi[cbase + row * 64 + sub * 8];
        *(short8*)&Cl[row * 72 + sub * 8] = *(const short8*)&Clo[cbase + row * 64 + sub * 8];
    }
    __syncthreads();
    // QK intra: S^T = P_c @ QM^T, masked v_loc > w_loc, packed to per-wave St strip
    #pragma unroll
    for (int ct = 0; ct < 4; ++ct) {
        short8 a0 = *(const short8*)&Ps[(ct * 16 + c) * 72 + q * 8];
        short8 a1 = *(const short8*)&Ps[(ct * 16 + c) * 72 + 32 + q * 8];
        f32x4 s = {};
        s = __builtin_amdgcn_mfma_f32_16x16x32_bf16(a0, bq0, s, 0, 0, 0);
        s = __builtin_amdgcn_mfma_f32_16x16x32_bf16(a1, bq1, s, 0, 0, 0);
        int vb = ct * 16 + q * 4, wl = wave * 16 + c;
        s16x4 pk;
        #pragma unroll
        for (int r = 0; r < 4; ++r) {
            float v = s[r];
            if (vb + r > wl) v = 0.f;
            pk[r] = f2bf(v);
        }
        *(s16x4*)&St[wave][c * 72 + ct * 16 + q * 4] = pk;
    }
    __syncthreads();                  // St visible (round-4 lesson: no barrier-free LDS RAW)
    // PV intra + QM @ C_hi + QM @ C_lo
    f32x4 oc[4] = {};
    short8 as0 = *(const short8*)&St[wave][c * 72 + q * 8];
    short8 as1 = *(const short8*)&St[wave][c * 72 + 32 + q * 8];
    #pragma unroll
    for (int tj = 0; tj < 4; ++tj) {
        short8 bp0 = *(const short8*)&Pt_s[(tj * 16 + c) * 72 + q * 8];
        short8 bp1 = *(const short8*)&Pt_s[(tj * 16 + c) * 72 + 32 + q * 8];
        oc[tj] = __builtin_amdgcn_mfma_f32_16x16x32_bf16(as0, bp0, oc[tj], 0, 0, 0);
        oc[tj] = __builtin_amdgcn_mfma_f32_16x16x32_bf16(as1, bp1, oc[tj], 0, 0, 0);
        short8 bh0 = *(const short8*)&Ch[(tj * 16 + c) * 72 + q * 8];
        short8 bh1 = *(const short8*)&Ch[(tj * 16 + c) * 72 + 32 + q * 8];
        oc[tj] = __builtin_amdgcn_mfma_f32_16x16x32_bf16(bq0, bh0, oc[tj], 0, 0, 0);
        oc[tj] = __builtin_amdgcn_mfma_f32_16x16x32_bf16(bq1, bh1, oc[tj], 0, 0, 0);
        short8 bl0 = *(const short8*)&Cl[(tj * 16 + c) * 72 + q * 8];
        short8 bl1 = *(const short8*)&Cl[(tj * 16 + c) * 72 + 32 + q * 8];
        oc[tj] = __builtin_amdgcn_mfma_f32_16x16x32_bf16(bq0, bl0, oc[tj], 0, 0, 0);
        oc[tj] = __builtin_amdgcn_mfma_f32_16x16x32_bf16(bq1, bl1, oc[tj], 0, 0, 0);
    }
    #pragma unroll
    for (int tj = 0; tj < 4; ++tj)
        #pragma unroll
        for (int r = 0; r < 4; ++r)
            Nd[(size_t)(w0g + wave * 16 + q * 4 + r) * C_ + n * KH + tj * 16 + c] = f2bf(oc[tj][r]);
}

extern "C" void kernel_launch(void* const* d_in, const int* in_sizes, int n_in,
                              void* d_out, int out_size, void* d_ws, size_t ws_size,
                              hipStream_t stream) {
    const float* x  = (const float*)d_in[0];
    const float* Wp = (const float*)d_in[1];
    const float* Pm = (const float*)d_in[2];
    const float* Tr = (const float*)d_in[3];
    const float* Wm = (const float*)d_in[4];
    float* out = (float*)d_out;
    char* ws = (char*)d_ws;

    const size_t MB = 1024 * 1024;
    float* metric = (float*)ws;                        // 256 KB
    short* wcat  = (short*)(ws + 256 * 1024);          // 4 MB: [Wp(1024) ; Wq(1024)] x 1024
    short* wp16  = wcat;
    short* wq16  = wcat + C_ * C_;
    short* wf16  = (short*)(ws + 256 * 1024 + 4 * MB); // 2 MB
    short* x16   = (short*)(ws + 256 * 1024 + 6 * MB); // 16 MB (aliased by nd16 later)
    short* pjqm  = (short*)(ws + 256 * 1024 + 22 * MB);// 32 MB: [8192][2048] = [proj | qm]
    short* nd16  = x16;                                // x16 dead after concat GEMM
    short* Chi   = (short*)d_out;                      // d_out as scratch: 16.75 MB
    short* Clo   = Chi + 8 * MB;                       // 16.75 MB (exactly fills d_out)

    k_metric<<<dim3(NH), dim3(256), 0, stream>>>(Pm, metric);
    k_wq<<<dim3(16, NH), dim3(256), 0, stream>>>(metric, Wp, wq16);
    k_wf<<<dim3(16, NH), dim3(256), 0, stream>>>(Tr, Wm, wf16);
    k_cvt<<<dim3(8192), dim3(256), 0, stream>>>(x, x16, (B_ * W_ * C_) / 4);
    k_cvt<<<dim3(1024), dim3(256), 0, stream>>>(Wp, wp16, (C_ * C_) / 4);

    k_gemm<2048, false><<<dim3(16, 64), dim3(256), 0, stream>>>(x16, wcat, (void*)pjqm);
    k_prefix<<<dim3(64), dim3(256), 0, stream>>>(pjqm, Chi, Clo);
    k_chunk<<<dim3(32, NH, B_), dim3(256), 0, stream>>>(pjqm, Chi, Clo, nd16);
    k_gemm<1024, true><<<dim3(8, 64), dim3(256), 0, stream>>>(nd16, wf16, (void*)out);
}